// Round 3
// baseline (4033.113 us; speedup 1.0000x reference)
//
#include <hip/hip_runtime.h>
#include <hip/hip_bf16.h>

// ============================================================================
// Net_72662256713812 — round 2: outputs are FLOAT32 (reference returns
// jnp.float32; harness doc: output dtype follows reference). Round 1 wrote
// bf16 into an f32-typed buffer -> plausible-magnitude garbage (err 3.13).
// Pipeline unchanged:
//  - top-1 MoE with token bucketing (4x less FFN work than dense reference)
//  - generic tiled f32 GEMM (128x64x16, 256 thr, 8x4 microtile) w/ template
//    flags: expert segments, gather, scatter+gate, relu, bias
//  - LDS attention core, fused FSMN / LN / PE elementwise
// ============================================================================

using bf = __hip_bfloat16;

#define B_ 4
#define T_ 512
#define IN_ 80
#define OUT_ 4096
#define D_ 512
#define HID_ 1024
#define E_ 4
#define H_ 8
#define DH_ 64
#define M_ 64
#define BT_ (B_ * T_)        // 2048
#define TKV_ (T_ + M_)       // 576

// ---------------------------------------------------------------- GEMM core
#define TM 128
#define TN 64
#define TK 16

template<bool EXPERT, bool GATHER, bool SCATTER, bool RELU, bool BIAS>
__global__ __launch_bounds__(256) void gemm_k(
    const float* __restrict__ A, int lda,
    const float* __restrict__ Bw,         // [K,N] row-major (+ e*K*N if EXPERT)
    const float* __restrict__ bias,       // [N] (+ e*N if EXPERT)
    float* __restrict__ C, int ldc,
    int M, int N, int K,
    const int* __restrict__ seg, const int* __restrict__ sorted,
    const float* __restrict__ scale, int remM)   // remM!=0: crow = m + (m>>9)*remM
{
    __shared__ float As[TK][TM + 4];
    __shared__ float Bs[TK][TN + 4];

    int e = EXPERT ? blockIdx.z : 0;
    int row0 = 0, cnt = M;
    if (EXPERT) { row0 = seg[e]; cnt = seg[e + 1] - row0; }
    int m0 = blockIdx.y * TM;
    if (m0 >= cnt) return;
    int n0 = blockIdx.x * TN;
    const float* Bp = Bw + (EXPERT ? (size_t)e * K * N : 0);

    int tid = threadIdx.x;
    int ak = tid & 15;          // k-col for A staging
    int am = tid >> 4;          // A staging rows: am + 16*i
    const float* aptr[8];
#pragma unroll
    for (int i = 0; i < 8; i++) {
        int m = m0 + am + 16 * i;
        int srow;
        if (EXPERT) {
            int mm = (m < cnt) ? m : (cnt - 1);   // clamp (values unused)
            int ci = row0 + mm;
            srow = GATHER ? sorted[ci] : ci;
        } else srow = m;
        aptr[i] = A + (size_t)srow * lda;
    }
    int bc = tid & 63, bk0 = tid >> 6;
    int tx = tid & 15, ty = tid >> 4;   // compute: rows ty*8..+7, cols tx*4..+3

    float acc[8][4];
#pragma unroll
    for (int j = 0; j < 8; j++)
#pragma unroll
        for (int i = 0; i < 4; i++) acc[j][i] = 0.f;

    for (int k0 = 0; k0 < K; k0 += TK) {
#pragma unroll
        for (int i = 0; i < 8; i++) As[ak][am + 16 * i] = aptr[i][k0 + ak];
#pragma unroll
        for (int i = 0; i < 4; i++)
            Bs[bk0 + 4 * i][bc] = Bp[(size_t)(k0 + bk0 + 4 * i) * N + n0 + bc];
        __syncthreads();
#pragma unroll
        for (int kk = 0; kk < TK; kk++) {
            float4 a0 = *(const float4*)&As[kk][ty * 8];
            float4 a1 = *(const float4*)&As[kk][ty * 8 + 4];
            float4 b0 = *(const float4*)&Bs[kk][tx * 4];
            float av[8] = {a0.x, a0.y, a0.z, a0.w, a1.x, a1.y, a1.z, a1.w};
            float bv[4] = {b0.x, b0.y, b0.z, b0.w};
#pragma unroll
            for (int j = 0; j < 8; j++)
#pragma unroll
                for (int i = 0; i < 4; i++) acc[j][i] += av[j] * bv[i];
        }
        __syncthreads();
    }

#pragma unroll
    for (int j = 0; j < 8; j++) {
        int m = m0 + ty * 8 + j;
        if (EXPERT && m >= cnt) continue;
        size_t crow; float sc = 1.f;
        if (SCATTER) { int tok = sorted[row0 + m]; crow = (size_t)tok; sc = scale[tok]; }
        else if (EXPERT) crow = (size_t)(row0 + m);
        else { crow = (size_t)m; if (remM) crow = (size_t)m + (size_t)(m >> 9) * remM; }
        float vout[4];
#pragma unroll
        for (int i = 0; i < 4; i++) {
            float v = acc[j][i];
            if (BIAS) v += bias[(EXPERT ? (size_t)e * N : 0) + n0 + tx * 4 + i];
            if (RELU) v = fmaxf(v, 0.f);
            if (SCATTER) v *= sc;
            vout[i] = v;
        }
        *(float4*)&C[crow * ldc + n0 + tx * 4] = make_float4(vout[0], vout[1], vout[2], vout[3]);
    }
}

// ---------------------------------------------------------------- small ops
__global__ void zero_k(float* p, int n) {
    int i = blockIdx.x * 256 + threadIdx.x;
    if (i < n) p[i] = 0.f;
}

// one wave per token: logits = embed[tok] @ router[D,4]; softmax; top-1; imp
__global__ void router_k(const float* __restrict__ embed, const float* __restrict__ rw,
                         const int* __restrict__ seq_len,
                         int* __restrict__ eid, float* __restrict__ gatev,
                         float* __restrict__ imp)
{
    int w = threadIdx.x >> 6, lane = threadIdx.x & 63;
    int tok = blockIdx.x * 4 + w;
    const float* er = embed + (size_t)tok * D_;
    float a0 = 0, a1 = 0, a2 = 0, a3 = 0;
    for (int d = lane; d < D_; d += 64) {
        float ev = er[d];
        a0 += ev * rw[d * 4 + 0];
        a1 += ev * rw[d * 4 + 1];
        a2 += ev * rw[d * 4 + 2];
        a3 += ev * rw[d * 4 + 3];
    }
    for (int off = 32; off; off >>= 1) {
        a0 += __shfl_xor(a0, off); a1 += __shfl_xor(a1, off);
        a2 += __shfl_xor(a2, off); a3 += __shfl_xor(a3, off);
    }
    if (lane == 0) {
        float lg[4] = {a0, a1, a2, a3};
        float mx = fmaxf(fmaxf(lg[0], lg[1]), fmaxf(lg[2], lg[3]));
        float g[4], s = 0.f;
        for (int e = 0; e < 4; e++) { g[e] = expf(lg[e] - mx); s += g[e]; }
        float inv = 1.f / s;
        int am = 0; float bv = g[0];
        for (int e = 1; e < 4; e++) if (g[e] > bv) { bv = g[e]; am = e; }  // first-max tie-break
        eid[tok] = am; gatev[tok] = bv * inv;
        int b = tok >> 9, t = tok & 511;
        if (t < seq_len[b])
            for (int e = 0; e < 4; e++) atomicAdd(&imp[e], g[e] * inv);
    }
}

// single block: bucket tokens by expert into sorted[], write seg[E+1]
__global__ void bucket_k(const int* __restrict__ eid, int* __restrict__ sorted,
                         int* __restrict__ seg)
{
    __shared__ int cnt[E_]; __shared__ int cur[E_];
    int tid = threadIdx.x;
    if (tid < E_) cnt[tid] = 0;
    __syncthreads();
    for (int t = tid; t < BT_; t += 256) atomicAdd(&cnt[eid[t]], 1);
    __syncthreads();
    if (tid == 0) {
        int o = 0;
        for (int e = 0; e < E_; e++) { seg[e] = o; cur[e] = o; o += cnt[e]; }
        seg[E_] = o;
    }
    __syncthreads();
    for (int t = tid; t < BT_; t += 256) {
        int pos = atomicAdd(&cur[eid[t]], 1);
        sorted[pos] = t;
    }
}

// m[t] = p[t] + sum_k fb[k]*p[t-2(k+1)] + fa[0]*p[t+1] (+ cur if skip) -> cur
__global__ void fsmn_k(const float* __restrict__ p, const float* __restrict__ fb,
                       const float* __restrict__ fa, float* __restrict__ cur, int skip)
{
    int idx = blockIdx.x * 256 + threadIdx.x;     // over BT_*D_
    int d = idx & 511;
    int t = (idx >> 9) & 511;
    float m = p[idx];
#pragma unroll
    for (int k = 0; k < 4; k++) {
        int tt = t - 2 * (k + 1);
        if (tt >= 0) m += fb[k * D_ + d] * p[idx - D_ * 2 * (k + 1)];
    }
    if (t + 1 < T_) m += fa[d] * p[idx + D_];
    if (skip) m += cur[idx];
    cur[idx] = m;
}

__global__ void addpe_k(float* __restrict__ cur) {
    int idx = blockIdx.x * 256 + threadIdx.x;
    int d = idx & 511, t = (idx >> 9) & 511;
    float div = expf((float)(d & ~1) * (-9.210340371976184f / (float)D_));
    float ang = (float)t * div;
    cur[idx] += (d & 1) ? cosf(ang) : sinf(ang);
}

// broadcast memory K/V rows (rows T_..T_+M_-1 of each batch)
__global__ void fillmem_k(const float* __restrict__ mk, const float* __restrict__ mv,
                          float* __restrict__ kbuf, float* __restrict__ vbuf)
{
    int idx = blockIdx.x * 256 + threadIdx.x;     // over B_*M_*D_
    int d = idx & 511, m = (idx >> 9) & 63, b = idx >> 15;
    size_t row = (size_t)b * TKV_ + T_ + m;
    kbuf[row * D_ + d] = mk[m * D_ + d];
    vbuf[row * D_ + d] = mv[m * D_ + d];
}

// attention core: one block = (b, h, 4 q rows); full 576-key softmax in LDS
__global__ __launch_bounds__(256) void attn_k(
    const float* __restrict__ q, const float* __restrict__ kbuf,
    const float* __restrict__ vbuf, const int* __restrict__ seq_len,
    float* __restrict__ attno)
{
    __shared__ float kv[64][68];     // k-pass: [d][key] transposed; v-pass: [key][d]
    __shared__ float qs[4][64];
    __shared__ float sc[4][TKV_];
    int b = blockIdx.z, h = blockIdx.y, t0 = blockIdx.x * 4;
    int tid = threadIdx.x, w = tid >> 6, lane = tid & 63;
    {
        int r = tid >> 6, d = tid & 63;
        qs[r][d] = q[((size_t)(b * T_) + t0 + r) * D_ + h * DH_ + d] * 0.125f;
    }
    int sl = seq_len[b];
    for (int s0 = 0; s0 < TKV_; s0 += 64) {
        __syncthreads();
#pragma unroll
        for (int i = 0; i < 16; i++) {
            int idx = tid + 256 * i;
            int key = idx >> 6, d = idx & 63;
            kv[d][key] = kbuf[((size_t)b * TKV_ + s0 + key) * D_ + h * DH_ + d];
        }
        __syncthreads();
        float acc = 0.f;
#pragma unroll 16
        for (int d = 0; d < 64; d++) acc += qs[w][d] * kv[d][lane];
        int sa = s0 + lane;
        sc[w][sa] = (sa >= T_ || sa < sl) ? acc : -1e9f;
    }
    __syncthreads();
    float mx = -1e30f;
    for (int s = lane; s < TKV_; s += 64) mx = fmaxf(mx, sc[w][s]);
    for (int off = 32; off; off >>= 1) mx = fmaxf(mx, __shfl_xor(mx, off));
    float sum = 0.f;
    for (int s = lane; s < TKV_; s += 64) { float e = expf(sc[w][s] - mx); sc[w][s] = e; sum += e; }
    for (int off = 32; off; off >>= 1) sum += __shfl_xor(sum, off);
    float inv = 1.f / sum;
    float o = 0.f;
    for (int s0 = 0; s0 < TKV_; s0 += 64) {
        __syncthreads();
#pragma unroll
        for (int i = 0; i < 16; i++) {
            int idx = tid + 256 * i;
            int key = idx >> 6, d = idx & 63;
            kv[key][d] = vbuf[((size_t)b * TKV_ + s0 + key) * D_ + h * DH_ + d];
        }
        __syncthreads();
#pragma unroll 16
        for (int j = 0; j < 64; j++) o += sc[w][s0 + j] * kv[j][lane];
    }
    attno[((size_t)(b * T_) + t0 + w) * D_ + h * DH_ + lane] = o * inv;
}

// cur = LN(cur + o_proj) * g + b, one wave per row
__global__ void ln_k(const float* __restrict__ o, const float* __restrict__ g,
                     const float* __restrict__ bb, float* __restrict__ cur)
{
    int w = threadIdx.x >> 6, lane = threadIdx.x & 63;
    size_t row = (size_t)(blockIdx.x * 4 + w);
    float v[8]; float s = 0.f;
#pragma unroll
    for (int i = 0; i < 8; i++) {
        int d = lane + 64 * i;
        v[i] = cur[row * D_ + d] + o[row * D_ + d];
        s += v[i];
    }
    for (int off = 32; off; off >>= 1) s += __shfl_xor(s, off);
    float mu = s * (1.f / D_);
    float vs = 0.f;
#pragma unroll
    for (int i = 0; i < 8; i++) { float dd = v[i] - mu; vs += dd * dd; }
    for (int off = 32; off; off >>= 1) vs += __shfl_xor(vs, off);
    float rstd = rsqrtf(vs * (1.f / D_) + 1e-5f);
#pragma unroll
    for (int i = 0; i < 8; i++) {
        int d = lane + 64 * i;
        cur[row * D_ + d] = (v[i] - mu) * rstd * g[d] + bb[d];
    }
}

__global__ void aux_k(const float* __restrict__ imp, float* __restrict__ outp) {
    if (threadIdx.x == 0) {
        float total = 0.f;
        for (int l = 0; l < 8; l++) {
            const float* ip = imp + l * 4;
            float m = (ip[0] + ip[1] + ip[2] + ip[3]) * 0.25f;
            float var = 0.f;
            for (int e = 0; e < 4; e++) { float d = ip[e] - m; var += d * d; }
            var *= 0.25f;
            total += var / (m * m + 1e-9f);
        }
        *outp = total;
    }
}

// ============================================================================
extern "C" void kernel_launch(void* const* d_in, const int* in_sizes, int n_in,
                              void* d_out, int out_size, void* d_ws, size_t ws_size,
                              hipStream_t stream)
{
    (void)in_sizes; (void)n_in; (void)out_size; (void)ws_size;
    const float* x        = (const float*)d_in[0];
    const int*   seqlen   = (const int*)d_in[1];
    const float* emb_w1   = (const float*)d_in[2];
    const float* emb_b1   = (const float*)d_in[3];
    const float* emb_w2   = (const float*)d_in[4];
    const float* emb_wo   = (const float*)d_in[5];
    const float* f0_w1    = (const float*)d_in[6];
    const float* f0_b1    = (const float*)d_in[7];
    const float* f0_w2    = (const float*)d_in[8];
    const float* f0_router= (const float*)d_in[9];
    const float* f0_fb    = (const float*)d_in[10];
    const float* f0_fa    = (const float*)d_in[11];
    const float* f_w1     = (const float*)d_in[12];
    const float* f_b1     = (const float*)d_in[13];
    const float* f_w2     = (const float*)d_in[14];
    const float* f_router = (const float*)d_in[15];
    const float* f_fb     = (const float*)d_in[16];
    const float* f_fa     = (const float*)d_in[17];
    const float* attn_wq  = (const float*)d_in[18];
    const float* attn_wk  = (const float*)d_in[19];
    const float* attn_wv  = (const float*)d_in[20];
    const float* attn_wo  = (const float*)d_in[21];
    const float* attn_mk  = (const float*)d_in[22];
    const float* attn_mv  = (const float*)d_in[23];
    const float* ln_g     = (const float*)d_in[24];
    const float* ln_b     = (const float*)d_in[25];
    const float* out_w    = (const float*)d_in[26];
    const float* out_b    = (const float*)d_in[27];

    float* out0 = (float*)d_out;                 // [2048,4096]
    float* out1 = out0 + (size_t)BT_ * OUT_;     // embed_out [2048,4096]
    float* out2 = out1 + (size_t)BT_ * OUT_;     // aux scalar

    // ---- workspace layout (f32) ----
    float* fws = (float*)d_ws;
    size_t o = 0;
    float* embedF = fws + o; o += (size_t)BT_ * D_;      // persists whole run
    float* curB   = fws + o; o += (size_t)BT_ * D_;
    float* hbuf   = fws + o; o += (size_t)BT_ * HID_;    // also attno|tmpo in attention
    float* pbuf   = fws + o; o += (size_t)BT_ * D_;      // also q in attention
    float* kbuf   = fws + o; o += (size_t)B_ * TKV_ * D_;
    float* vbuf   = fws + o; o += (size_t)B_ * TKV_ * D_;
    float* gatev  = fws + o; o += BT_;
    float* impA   = fws + o; o += 32;
    int* eid    = (int*)(fws + o); o += BT_;
    int* sorted = (int*)(fws + o); o += BT_;
    int* seg    = (int*)(fws + o); o += 8;
    float* qbuf  = pbuf;
    float* attno = hbuf;
    float* tmpo  = hbuf + (size_t)BT_ * D_;

    zero_k<<<1, 64, 0, stream>>>(impA, 32);

    // embed sub-network
    gemm_k<false,false,false,true,true><<<dim3(HID_/TN, BT_/TM, 1), 256, 0, stream>>>(
        x, IN_, emb_w1, emb_b1, hbuf, HID_, BT_, HID_, IN_,
        nullptr, nullptr, nullptr, 0);
    gemm_k<false,false,false,false,false><<<dim3(D_/TN, BT_/TM, 1), 256, 0, stream>>>(
        hbuf, HID_, emb_w2, nullptr, embedF, D_, BT_, D_, HID_,
        nullptr, nullptr, nullptr, 0);
    gemm_k<false,false,false,false,false><<<dim3(OUT_/TN, BT_/TM, 1), 256, 0, stream>>>(
        embedF, D_, emb_wo, nullptr, out1, OUT_, BT_, OUT_, D_,
        nullptr, nullptr, nullptr, 0);

    for (int l = 0; l < 8; l++) {
        const float* rw  = (l == 0) ? f0_router : f_router + (size_t)(l-1) * D_ * E_;
        const float* w1  = (l == 0) ? f0_w1 : f_w1 + (size_t)(l-1) * E_ * D_ * HID_;
        const float* b1p = (l == 0) ? f0_b1 : f_b1 + (size_t)(l-1) * E_ * HID_;
        const float* w2  = (l == 0) ? f0_w2 : f_w2 + (size_t)(l-1) * E_ * HID_ * D_;
        const float* fbp = (l == 0) ? f0_fb : f_fb + (size_t)(l-1) * 4 * D_;
        const float* fap = (l == 0) ? f0_fa : f_fa + (size_t)(l-1) * 1 * D_;
        int Kl = (l == 0) ? IN_ : D_;
        const float* Ain = (l == 0) ? x : curB;

        router_k<<<BT_/4, 256, 0, stream>>>(embedF, rw, seqlen, eid, gatev, impA + l*4);
        bucket_k<<<1, 256, 0, stream>>>(eid, sorted, seg);
        // h = relu(gather(Ain) @ w1[e] + b1[e])   (compact rows)
        gemm_k<true,true,false,true,true><<<dim3(HID_/TN, BT_/TM, E_), 256, 0, stream>>>(
            Ain, Kl, w1, b1p, hbuf, HID_, BT_, HID_, Kl, seg, sorted, nullptr, 0);
        // p[token] = gate[token] * (h @ w2[e])    (scatter)
        gemm_k<true,false,true,false,false><<<dim3(D_/TN, BT_/TM, E_), 256, 0, stream>>>(
            hbuf, HID_, w2, nullptr, pbuf, D_, BT_, D_, HID_, seg, sorted, gatev, 0);
        fsmn_k<<<BT_*D_/256, 256, 0, stream>>>(pbuf, fbp, fap, curB, (l > 0) ? 1 : 0);

        if (l == 3) addpe_k<<<BT_*D_/256, 256, 0, stream>>>(curB);

        if (l == 3 || l == 7) {
            int ab = (l == 3) ? 0 : 1;
            const float* wq = attn_wq + (size_t)ab * D_ * D_;
            const float* wk = attn_wk + (size_t)ab * D_ * D_;
            const float* wv = attn_wv + (size_t)ab * D_ * D_;
            const float* wo = attn_wo + (size_t)ab * D_ * D_;
            const float* mk = attn_mk + (size_t)ab * M_ * D_;
            const float* mv = attn_mv + (size_t)ab * M_ * D_;
            const float* g  = ln_g + (size_t)ab * D_;
            const float* bb = ln_b + (size_t)ab * D_;

            gemm_k<false,false,false,false,false><<<dim3(D_/TN, BT_/TM, 1), 256, 0, stream>>>(
                curB, D_, wq, nullptr, qbuf, D_, BT_, D_, D_, nullptr, nullptr, nullptr, 0);
            gemm_k<false,false,false,false,false><<<dim3(D_/TN, BT_/TM, 1), 256, 0, stream>>>(
                curB, D_, wk, nullptr, kbuf, D_, BT_, D_, D_, nullptr, nullptr, nullptr, M_);
            gemm_k<false,false,false,false,false><<<dim3(D_/TN, BT_/TM, 1), 256, 0, stream>>>(
                curB, D_, wv, nullptr, vbuf, D_, BT_, D_, D_, nullptr, nullptr, nullptr, M_);
            fillmem_k<<<B_*M_*D_/256, 256, 0, stream>>>(mk, mv, kbuf, vbuf);
            attn_k<<<dim3(T_/4, H_, B_), 256, 0, stream>>>(qbuf, kbuf, vbuf, seqlen, attno);
            gemm_k<false,false,false,false,false><<<dim3(D_/TN, BT_/TM, 1), 256, 0, stream>>>(
                attno, D_, wo, nullptr, tmpo, D_, BT_, D_, D_, nullptr, nullptr, nullptr, 0);
            ln_k<<<BT_/4, 256, 0, stream>>>(tmpo, g, bb, curB);
        }
    }

    // output head
    gemm_k<false,false,false,false,true><<<dim3(OUT_/TN, BT_/TM, 1), 256, 0, stream>>>(
        curB, D_, out_w, out_b, out0, OUT_, BT_, OUT_, D_,
        nullptr, nullptr, nullptr, 0);
    aux_k<<<1, 64, 0, stream>>>(impA, out2);
}

// Round 4
// 3744.645 us; speedup vs baseline: 1.0770x; 1.0770x over previous
//
#include <hip/hip_runtime.h>
#include <hip/hip_bf16.h>

// ============================================================================
// Net_72662256713812 — round 3: MFMA bf16 GEMMs + high-reuse attention.
//  - embed path (emb_w1, emb_w2) stays exact f32 VALU: all 8 MoE layers route
//    on the same embed; keeping it f32 makes expert argmax bit-match the ref.
//  - all other GEMMs: mfma_f32_16x16x32_bf16, 128x64x32 tile, 4 waves,
//    f32->bf16 LDS staging, XOR chunk swizzle (bank-conflict-free frag reads).
//  - attention: 16 q-rows/block (4/wave) -> 4x LDS/global reuse; stride-69
//    LDS padding (2-way conflicts only, free on CDNA4).
// ============================================================================

using bf = __hip_bfloat16;
typedef __bf16 bf16x8 __attribute__((ext_vector_type(8)));
typedef float f32x4 __attribute__((ext_vector_type(4)));

#define B_ 4
#define T_ 512
#define IN_ 80
#define OUT_ 4096
#define D_ 512
#define HID_ 1024
#define E_ 4
#define H_ 8
#define DH_ 64
#define M_ 64
#define BT_ (B_ * T_)        // 2048
#define TKV_ (T_ + M_)       // 576

// ---------------------------------------------------------------- f32 GEMM (embed path only)
#define TM 128
#define TN 64
#define TK 16

template<bool RELU, bool BIAS>
__global__ __launch_bounds__(256) void gemm_k(
    const float* __restrict__ A, int lda,
    const float* __restrict__ Bw, const float* __restrict__ bias,
    float* __restrict__ C, int ldc, int M, int N, int K)
{
    __shared__ float As[TK][TM + 4];
    __shared__ float Bs[TK][TN + 4];
    int m0 = blockIdx.y * TM, n0 = blockIdx.x * TN;
    int tid = threadIdx.x;
    int ak = tid & 15, am = tid >> 4;
    int bc = tid & 63, bk0 = tid >> 6;
    int tx = tid & 15, ty = tid >> 4;
    float acc[8][4];
#pragma unroll
    for (int j = 0; j < 8; j++)
#pragma unroll
        for (int i = 0; i < 4; i++) acc[j][i] = 0.f;
    for (int k0 = 0; k0 < K; k0 += TK) {
#pragma unroll
        for (int i = 0; i < 8; i++)
            As[ak][am + 16 * i] = A[(size_t)(m0 + am + 16 * i) * lda + k0 + ak];
#pragma unroll
        for (int i = 0; i < 4; i++)
            Bs[bk0 + 4 * i][bc] = Bw[(size_t)(k0 + bk0 + 4 * i) * N + n0 + bc];
        __syncthreads();
#pragma unroll
        for (int kk = 0; kk < TK; kk++) {
            float4 a0 = *(const float4*)&As[kk][ty * 8];
            float4 a1 = *(const float4*)&As[kk][ty * 8 + 4];
            float4 b0 = *(const float4*)&Bs[kk][tx * 4];
            float av[8] = {a0.x, a0.y, a0.z, a0.w, a1.x, a1.y, a1.z, a1.w};
            float bv[4] = {b0.x, b0.y, b0.z, b0.w};
#pragma unroll
            for (int j = 0; j < 8; j++)
#pragma unroll
                for (int i = 0; i < 4; i++) acc[j][i] += av[j] * bv[i];
        }
        __syncthreads();
    }
#pragma unroll
    for (int j = 0; j < 8; j++) {
        size_t crow = (size_t)(m0 + ty * 8 + j);
        float vout[4];
#pragma unroll
        for (int i = 0; i < 4; i++) {
            float v = acc[j][i];
            if (BIAS) v += bias[n0 + tx * 4 + i];
            if (RELU) v = fmaxf(v, 0.f);
            vout[i] = v;
        }
        *(float4*)&C[crow * ldc + n0 + tx * 4] = make_float4(vout[0], vout[1], vout[2], vout[3]);
    }
}

// ---------------------------------------------------------------- MFMA GEMM
#define MBM 128
#define MBN 64
#define MBK 32
#define LDAS 40   // bf16 elems per LDS row (32 + 8 pad; 80B = 16B-multiple)

__device__ __forceinline__ unsigned pk2(float a, float b) {
    unsigned short ua = __builtin_bit_cast(unsigned short, (__bf16)a);
    unsigned short ub = __builtin_bit_cast(unsigned short, (__bf16)b);
    return (unsigned)ua | ((unsigned)ub << 16);
}

template<bool EXPERT, bool GATHER, bool SCATTER, bool RELU, bool BIAS>
__global__ __launch_bounds__(256) void mgemm_k(
    const float* __restrict__ A, int lda,
    const float* __restrict__ Bw,         // [K,N] row-major (+ e*K*N if EXPERT)
    const float* __restrict__ bias,
    float* __restrict__ C, int ldc, int M, int N, int K,
    const int* __restrict__ seg, const int* __restrict__ sorted,
    const float* __restrict__ scale, int remM)
{
    __shared__ __align__(16) __bf16 As[MBM * LDAS];
    __shared__ __align__(16) __bf16 Bs[MBN * LDAS];

    int e = EXPERT ? blockIdx.z : 0;
    int row0 = 0, cnt = M;
    if (EXPERT) { row0 = seg[e]; cnt = seg[e + 1] - row0; }
    int m0 = blockIdx.y * MBM;
    if (m0 >= cnt) return;
    int n0 = blockIdx.x * MBN;
    const float* Bp = Bw + (EXPERT ? (size_t)e * K * N : 0);

    int tid = threadIdx.x;
    // A staging: row = tid>>1 (0..127), half = tid&1 -> k cols half*16 + 0..15
    int arow = tid >> 1, ahalf = tid & 1;
    const float* aptr;
    {
        int m = m0 + arow;
        int srow;
        if (EXPERT) { int mm = (m < cnt) ? m : (cnt - 1); int ci = row0 + mm;
                      srow = GATHER ? sorted[ci] : ci; }
        else srow = m;
        aptr = A + (size_t)srow * lda + ahalf * 16;
    }
    int asw = (arow >> 3) & 3;
    // B staging: n = tid&63, k-chunk = tid>>6 (8 k each)
    int bn = tid & 63, bkc = tid >> 6;
    int bcs = bkc ^ ((bn >> 3) & 3);

    int lane = tid & 63, wid = tid >> 6;
    int wm = wid & 1, wn = wid >> 1;
    int l15 = lane & 15, quad = lane >> 4;

    int aoff[4], boff[2];
#pragma unroll
    for (int mt = 0; mt < 4; mt++) {
        int m = wm * 64 + mt * 16 + l15;
        aoff[mt] = m * LDAS + (quad ^ ((m >> 3) & 3)) * 8;
    }
#pragma unroll
    for (int nt = 0; nt < 2; nt++) {
        int n = wn * 32 + nt * 16 + l15;
        boff[nt] = n * LDAS + (quad ^ ((n >> 3) & 3)) * 8;
    }

    f32x4 acc[4][2];
#pragma unroll
    for (int mt = 0; mt < 4; mt++)
#pragma unroll
        for (int nt = 0; nt < 2; nt++)
#pragma unroll
            for (int r = 0; r < 4; r++) acc[mt][nt][r] = 0.f;

    for (int k0 = 0; k0 < K; k0 += MBK) {
        // ---- stage A (2 chunks of 8 bf16 per thread)
#pragma unroll
        for (int cc = 0; cc < 2; cc++) {
            int kbase = k0 + ahalf * 16 + cc * 8;
            float4 f0, f1;
            if (kbase < K) {            // all K are multiples of 16 -> chunk-granular
                f0 = *(const float4*)(aptr + k0 + cc * 8);
                f1 = *(const float4*)(aptr + k0 + cc * 8 + 4);
            } else {
                f0 = make_float4(0.f, 0.f, 0.f, 0.f); f1 = f0;
            }
            uint4 pk = make_uint4(pk2(f0.x, f0.y), pk2(f0.z, f0.w),
                                  pk2(f1.x, f1.y), pk2(f1.z, f1.w));
            int cs = (ahalf * 2 + cc) ^ asw;
            *(uint4*)&As[arow * LDAS + cs * 8] = pk;
        }
        // ---- stage B (8 strided k-rows -> one transposed chunk)
        {
            float f[8];
            int kk = k0 + bkc * 8;
#pragma unroll
            for (int i = 0; i < 8; i++) {
                int k = kk + i;
                f[i] = (k < K) ? Bp[(size_t)k * N + n0 + bn] : 0.f;
            }
            uint4 pk = make_uint4(pk2(f[0], f[1]), pk2(f[2], f[3]),
                                  pk2(f[4], f[5]), pk2(f[6], f[7]));
            *(uint4*)&Bs[bn * LDAS + bcs * 8] = pk;
        }
        __syncthreads();
        bf16x8 af[4], bfm[2];
#pragma unroll
        for (int mt = 0; mt < 4; mt++) af[mt] = *(const bf16x8*)&As[aoff[mt]];
#pragma unroll
        for (int nt = 0; nt < 2; nt++) bfm[nt] = *(const bf16x8*)&Bs[boff[nt]];
#pragma unroll
        for (int mt = 0; mt < 4; mt++)
#pragma unroll
            for (int nt = 0; nt < 2; nt++)
                acc[mt][nt] = __builtin_amdgcn_mfma_f32_16x16x32_bf16(
                    af[mt], bfm[nt], acc[mt][nt], 0, 0, 0);
        __syncthreads();
    }

    // ---- epilogue: C/D layout col=lane&15, row=quad*4+reg
#pragma unroll
    for (int mt = 0; mt < 4; mt++) {
#pragma unroll
        for (int r = 0; r < 4; r++) {
            int mi = wm * 64 + mt * 16 + quad * 4 + r;
            int m = m0 + mi;
            if (EXPERT && m >= cnt) continue;
            size_t crow; float sc = 1.f;
            if (SCATTER) { int tok = sorted[row0 + m]; crow = (size_t)tok; sc = scale[tok]; }
            else if (EXPERT) crow = (size_t)(row0 + m);
            else { crow = (size_t)m; if (remM) crow = (size_t)m + (size_t)(m >> 9) * remM; }
#pragma unroll
            for (int nt = 0; nt < 2; nt++) {
                int col = n0 + wn * 32 + nt * 16 + l15;
                float v = acc[mt][nt][r];
                if (BIAS) v += bias[(EXPERT ? (size_t)e * N : 0) + col];
                if (RELU) v = fmaxf(v, 0.f);
                if (SCATTER) v *= sc;
                C[crow * (size_t)ldc + col] = v;
            }
        }
    }
}

// ---------------------------------------------------------------- small ops
__global__ void zero_k(float* p, int n) {
    int i = blockIdx.x * 256 + threadIdx.x;
    if (i < n) p[i] = 0.f;
}

__global__ void router_k(const float* __restrict__ embed, const float* __restrict__ rw,
                         const int* __restrict__ seq_len,
                         int* __restrict__ eid, float* __restrict__ gatev,
                         float* __restrict__ imp)
{
    int w = threadIdx.x >> 6, lane = threadIdx.x & 63;
    int tok = blockIdx.x * 4 + w;
    const float* er = embed + (size_t)tok * D_;
    float a0 = 0, a1 = 0, a2 = 0, a3 = 0;
    for (int d = lane; d < D_; d += 64) {
        float ev = er[d];
        a0 += ev * rw[d * 4 + 0];
        a1 += ev * rw[d * 4 + 1];
        a2 += ev * rw[d * 4 + 2];
        a3 += ev * rw[d * 4 + 3];
    }
    for (int off = 32; off; off >>= 1) {
        a0 += __shfl_xor(a0, off); a1 += __shfl_xor(a1, off);
        a2 += __shfl_xor(a2, off); a3 += __shfl_xor(a3, off);
    }
    if (lane == 0) {
        float lg[4] = {a0, a1, a2, a3};
        float mx = fmaxf(fmaxf(lg[0], lg[1]), fmaxf(lg[2], lg[3]));
        float g[4], s = 0.f;
        for (int e = 0; e < 4; e++) { g[e] = expf(lg[e] - mx); s += g[e]; }
        float inv = 1.f / s;
        int am = 0; float bv = g[0];
        for (int e = 1; e < 4; e++) if (g[e] > bv) { bv = g[e]; am = e; }
        eid[tok] = am; gatev[tok] = bv * inv;
        int b = tok >> 9, t = tok & 511;
        if (t < seq_len[b])
            for (int e = 0; e < 4; e++) atomicAdd(&imp[e], g[e] * inv);
    }
}

__global__ void bucket_k(const int* __restrict__ eid, int* __restrict__ sorted,
                         int* __restrict__ seg)
{
    __shared__ int cnt[E_]; __shared__ int cur[E_];
    int tid = threadIdx.x;
    if (tid < E_) cnt[tid] = 0;
    __syncthreads();
    for (int t = tid; t < BT_; t += 256) atomicAdd(&cnt[eid[t]], 1);
    __syncthreads();
    if (tid == 0) {
        int o = 0;
        for (int e = 0; e < E_; e++) { seg[e] = o; cur[e] = o; o += cnt[e]; }
        seg[E_] = o;
    }
    __syncthreads();
    for (int t = tid; t < BT_; t += 256) {
        int pos = atomicAdd(&cur[eid[t]], 1);
        sorted[pos] = t;
    }
}

__global__ void fsmn_k(const float* __restrict__ p, const float* __restrict__ fb,
                       const float* __restrict__ fa, float* __restrict__ cur, int skip)
{
    int idx = blockIdx.x * 256 + threadIdx.x;
    int d = idx & 511;
    int t = (idx >> 9) & 511;
    float m = p[idx];
#pragma unroll
    for (int k = 0; k < 4; k++) {
        int tt = t - 2 * (k + 1);
        if (tt >= 0) m += fb[k * D_ + d] * p[idx - D_ * 2 * (k + 1)];
    }
    if (t + 1 < T_) m += fa[d] * p[idx + D_];
    if (skip) m += cur[idx];
    cur[idx] = m;
}

__global__ void addpe_k(float* __restrict__ cur) {
    int idx = blockIdx.x * 256 + threadIdx.x;
    int d = idx & 511, t = (idx >> 9) & 511;
    float div = expf((float)(d & ~1) * (-9.210340371976184f / (float)D_));
    float ang = (float)t * div;
    cur[idx] += (d & 1) ? cosf(ang) : sinf(ang);
}

__global__ void fillmem_k(const float* __restrict__ mk, const float* __restrict__ mv,
                          float* __restrict__ kbuf, float* __restrict__ vbuf)
{
    int idx = blockIdx.x * 256 + threadIdx.x;
    int d = idx & 511, m = (idx >> 9) & 63, b = idx >> 15;
    size_t row = (size_t)b * TKV_ + T_ + m;
    kbuf[row * D_ + d] = mk[m * D_ + d];
    vbuf[row * D_ + d] = mv[m * D_ + d];
}

// attention: one block = (b, h, 16 q rows); 4 rows per wave
#define QR 16
__global__ __launch_bounds__(256) void attn_k(
    const float* __restrict__ q, const float* __restrict__ kbuf,
    const float* __restrict__ vbuf, const int* __restrict__ seq_len,
    float* __restrict__ attno)
{
    __shared__ float kv[64 * 69];     // score pass [d*69+key]; V pass [key*69+d]
    __shared__ float qs[QR][64];
    __shared__ float sc[QR][TKV_];
    int b = blockIdx.z, h = blockIdx.y, t0 = blockIdx.x * QR;
    int tid = threadIdx.x, w = tid >> 6, lane = tid & 63;
    int r0 = w * 4;
#pragma unroll
    for (int i = 0; i < 4; i++) {
        int idx = tid + 256 * i;
        int r = idx >> 6, d = idx & 63;
        qs[r][d] = q[((size_t)(b * T_) + t0 + r) * D_ + h * DH_ + d] * 0.125f;
    }
    int sl = seq_len[b];
    for (int s0 = 0; s0 < TKV_; s0 += 64) {
        __syncthreads();
#pragma unroll
        for (int i = 0; i < 16; i++) {
            int idx = tid + 256 * i;
            int key = idx >> 6, d = idx & 63;
            kv[d * 69 + key] = kbuf[((size_t)b * TKV_ + s0 + key) * D_ + h * DH_ + d];
        }
        __syncthreads();
        float a0 = 0, a1 = 0, a2 = 0, a3 = 0;
#pragma unroll 4
        for (int d = 0; d < 64; d++) {
            float kvv = kv[d * 69 + lane];
            a0 += qs[r0 + 0][d] * kvv;
            a1 += qs[r0 + 1][d] * kvv;
            a2 += qs[r0 + 2][d] * kvv;
            a3 += qs[r0 + 3][d] * kvv;
        }
        int sa = s0 + lane;
        bool ok = (sa >= T_ || sa < sl);
        sc[r0 + 0][sa] = ok ? a0 : -1e9f;
        sc[r0 + 1][sa] = ok ? a1 : -1e9f;
        sc[r0 + 2][sa] = ok ? a2 : -1e9f;
        sc[r0 + 3][sa] = ok ? a3 : -1e9f;
    }
    float inv[4];
#pragma unroll
    for (int r = 0; r < 4; r++) {
        float mx = -1e30f;
        for (int s = lane; s < TKV_; s += 64) mx = fmaxf(mx, sc[r0 + r][s]);
        for (int off = 32; off; off >>= 1) mx = fmaxf(mx, __shfl_xor(mx, off));
        float sum = 0.f;
        for (int s = lane; s < TKV_; s += 64) {
            float e2 = expf(sc[r0 + r][s] - mx); sc[r0 + r][s] = e2; sum += e2;
        }
        for (int off = 32; off; off >>= 1) sum += __shfl_xor(sum, off);
        inv[r] = 1.f / sum;
    }
    float o0 = 0, o1 = 0, o2 = 0, o3 = 0;
    for (int s0 = 0; s0 < TKV_; s0 += 64) {
        __syncthreads();
#pragma unroll
        for (int i = 0; i < 16; i++) {
            int idx = tid + 256 * i;
            int key = idx >> 6, d = idx & 63;
            kv[key * 69 + d] = vbuf[((size_t)b * TKV_ + s0 + key) * D_ + h * DH_ + d];
        }
        __syncthreads();
#pragma unroll 4
        for (int j = 0; j < 64; j++) {
            float vv = kv[j * 69 + lane];
            o0 += sc[r0 + 0][s0 + j] * vv;
            o1 += sc[r0 + 1][s0 + j] * vv;
            o2 += sc[r0 + 2][s0 + j] * vv;
            o3 += sc[r0 + 3][s0 + j] * vv;
        }
    }
    size_t base = ((size_t)(b * T_) + t0 + r0) * D_ + h * DH_ + lane;
    attno[base + 0 * D_] = o0 * inv[0];
    attno[base + 1 * D_] = o1 * inv[1];
    attno[base + 2 * D_] = o2 * inv[2];
    attno[base + 3 * D_] = o3 * inv[3];
}

__global__ void ln_k(const float* __restrict__ o, const float* __restrict__ g,
                     const float* __restrict__ bb, float* __restrict__ cur)
{
    int w = threadIdx.x >> 6, lane = threadIdx.x & 63;
    size_t row = (size_t)(blockIdx.x * 4 + w);
    float v[8]; float s = 0.f;
#pragma unroll
    for (int i = 0; i < 8; i++) {
        int d = lane + 64 * i;
        v[i] = cur[row * D_ + d] + o[row * D_ + d];
        s += v[i];
    }
    for (int off = 32; off; off >>= 1) s += __shfl_xor(s, off);
    float mu = s * (1.f / D_);
    float vs = 0.f;
#pragma unroll
    for (int i = 0; i < 8; i++) { float dd = v[i] - mu; vs += dd * dd; }
    for (int off = 32; off; off >>= 1) vs += __shfl_xor(vs, off);
    float rstd = rsqrtf(vs * (1.f / D_) + 1e-5f);
#pragma unroll
    for (int i = 0; i < 8; i++) {
        int d = lane + 64 * i;
        cur[row * D_ + d] = (v[i] - mu) * rstd * g[d] + bb[d];
    }
}

__global__ void aux_k(const float* __restrict__ imp, float* __restrict__ outp) {
    if (threadIdx.x == 0) {
        float total = 0.f;
        for (int l = 0; l < 8; l++) {
            const float* ip = imp + l * 4;
            float m = (ip[0] + ip[1] + ip[2] + ip[3]) * 0.25f;
            float var = 0.f;
            for (int e = 0; e < 4; e++) { float d = ip[e] - m; var += d * d; }
            var *= 0.25f;
            total += var / (m * m + 1e-9f);
        }
        *outp = total;
    }
}

// ============================================================================
extern "C" void kernel_launch(void* const* d_in, const int* in_sizes, int n_in,
                              void* d_out, int out_size, void* d_ws, size_t ws_size,
                              hipStream_t stream)
{
    (void)in_sizes; (void)n_in; (void)out_size; (void)ws_size;
    const float* x        = (const float*)d_in[0];
    const int*   seqlen   = (const int*)d_in[1];
    const float* emb_w1   = (const float*)d_in[2];
    const float* emb_b1   = (const float*)d_in[3];
    const float* emb_w2   = (const float*)d_in[4];
    const float* emb_wo   = (const float*)d_in[5];
    const float* f0_w1    = (const float*)d_in[6];
    const float* f0_b1    = (const float*)d_in[7];
    const float* f0_w2    = (const float*)d_in[8];
    const float* f0_router= (const float*)d_in[9];
    const float* f0_fb    = (const float*)d_in[10];
    const float* f0_fa    = (const float*)d_in[11];
    const float* f_w1     = (const float*)d_in[12];
    const float* f_b1     = (const float*)d_in[13];
    const float* f_w2     = (const float*)d_in[14];
    const float* f_router = (const float*)d_in[15];
    const float* f_fb     = (const float*)d_in[16];
    const float* f_fa     = (const float*)d_in[17];
    const float* attn_wq  = (const float*)d_in[18];
    const float* attn_wk  = (const float*)d_in[19];
    const float* attn_wv  = (const float*)d_in[20];
    const float* attn_wo  = (const float*)d_in[21];
    const float* attn_mk  = (const float*)d_in[22];
    const float* attn_mv  = (const float*)d_in[23];
    const float* ln_g     = (const float*)d_in[24];
    const float* ln_b     = (const float*)d_in[25];
    const float* out_w    = (const float*)d_in[26];
    const float* out_b    = (const float*)d_in[27];

    float* out0 = (float*)d_out;
    float* out1 = out0 + (size_t)BT_ * OUT_;
    float* out2 = out1 + (size_t)BT_ * OUT_;

    float* fws = (float*)d_ws;
    size_t o = 0;
    float* embedF = fws + o; o += (size_t)BT_ * D_;
    float* curB   = fws + o; o += (size_t)BT_ * D_;
    float* hbuf   = fws + o; o += (size_t)BT_ * HID_;
    float* pbuf   = fws + o; o += (size_t)BT_ * D_;
    float* kbuf   = fws + o; o += (size_t)B_ * TKV_ * D_;
    float* vbuf   = fws + o; o += (size_t)B_ * TKV_ * D_;
    float* gatev  = fws + o; o += BT_;
    float* impA   = fws + o; o += 32;
    int* eid    = (int*)(fws + o); o += BT_;
    int* sorted = (int*)(fws + o); o += BT_;
    int* seg    = (int*)(fws + o); o += 8;
    float* qbuf  = pbuf;
    float* attno = hbuf;
    float* tmpo  = hbuf + (size_t)BT_ * D_;

    zero_k<<<1, 64, 0, stream>>>(impA, 32);

    // embed sub-network — exact f32 (routing determinism)
    gemm_k<true,true><<<dim3(HID_/TN, BT_/TM, 1), 256, 0, stream>>>(
        x, IN_, emb_w1, emb_b1, hbuf, HID_, BT_, HID_, IN_);
    gemm_k<false,false><<<dim3(D_/TN, BT_/TM, 1), 256, 0, stream>>>(
        hbuf, HID_, emb_w2, nullptr, embedF, D_, BT_, D_, HID_);
    // embed_out head — MFMA
    mgemm_k<false,false,false,false,false><<<dim3(OUT_/MBN, BT_/MBM, 1), 256, 0, stream>>>(
        embedF, D_, emb_wo, nullptr, out1, OUT_, BT_, OUT_, D_,
        nullptr, nullptr, nullptr, 0);

    for (int l = 0; l < 8; l++) {
        const float* rw  = (l == 0) ? f0_router : f_router + (size_t)(l-1) * D_ * E_;
        const float* w1  = (l == 0) ? f0_w1 : f_w1 + (size_t)(l-1) * E_ * D_ * HID_;
        const float* b1p = (l == 0) ? f0_b1 : f_b1 + (size_t)(l-1) * E_ * HID_;
        const float* w2  = (l == 0) ? f0_w2 : f_w2 + (size_t)(l-1) * E_ * HID_ * D_;
        const float* fbp = (l == 0) ? f0_fb : f_fb + (size_t)(l-1) * 4 * D_;
        const float* fap = (l == 0) ? f0_fa : f_fa + (size_t)(l-1) * 1 * D_;
        int Kl = (l == 0) ? IN_ : D_;
        const float* Ain = (l == 0) ? x : curB;

        router_k<<<BT_/4, 256, 0, stream>>>(embedF, rw, seqlen, eid, gatev, impA + l*4);
        bucket_k<<<1, 256, 0, stream>>>(eid, sorted, seg);
        mgemm_k<true,true,false,true,true><<<dim3(HID_/MBN, BT_/MBM, E_), 256, 0, stream>>>(
            Ain, Kl, w1, b1p, hbuf, HID_, BT_, HID_, Kl, seg, sorted, nullptr, 0);
        mgemm_k<true,false,true,false,false><<<dim3(D_/MBN, BT_/MBM, E_), 256, 0, stream>>>(
            hbuf, HID_, w2, nullptr, pbuf, D_, BT_, D_, HID_, seg, sorted, gatev, 0);
        fsmn_k<<<BT_*D_/256, 256, 0, stream>>>(pbuf, fbp, fap, curB, (l > 0) ? 1 : 0);

        if (l == 3) addpe_k<<<BT_*D_/256, 256, 0, stream>>>(curB);

        if (l == 3 || l == 7) {
            int ab = (l == 3) ? 0 : 1;
            const float* wq = attn_wq + (size_t)ab * D_ * D_;
            const float* wk = attn_wk + (size_t)ab * D_ * D_;
            const float* wv = attn_wv + (size_t)ab * D_ * D_;
            const float* wo = attn_wo + (size_t)ab * D_ * D_;
            const float* mk = attn_mk + (size_t)ab * M_ * D_;
            const float* mv = attn_mv + (size_t)ab * M_ * D_;
            const float* g  = ln_g + (size_t)ab * D_;
            const float* bb = ln_b + (size_t)ab * D_;

            mgemm_k<false,false,false,false,false><<<dim3(D_/MBN, BT_/MBM, 1), 256, 0, stream>>>(
                curB, D_, wq, nullptr, qbuf, D_, BT_, D_, D_, nullptr, nullptr, nullptr, 0);
            mgemm_k<false,false,false,false,false><<<dim3(D_/MBN, BT_/MBM, 1), 256, 0, stream>>>(
                curB, D_, wk, nullptr, kbuf, D_, BT_, D_, D_, nullptr, nullptr, nullptr, M_);
            mgemm_k<false,false,false,false,false><<<dim3(D_/MBN, BT_/MBM, 1), 256, 0, stream>>>(
                curB, D_, wv, nullptr, vbuf, D_, BT_, D_, D_, nullptr, nullptr, nullptr, M_);
            fillmem_k<<<B_*M_*D_/256, 256, 0, stream>>>(mk, mv, kbuf, vbuf);
            attn_k<<<dim3(T_/QR, H_, B_), 256, 0, stream>>>(qbuf, kbuf, vbuf, seqlen, attno);
            mgemm_k<false,false,false,false,false><<<dim3(D_/MBN, BT_/MBM, 1), 256, 0, stream>>>(
                attno, D_, wo, nullptr, tmpo, D_, BT_, D_, D_, nullptr, nullptr, nullptr, 0);
            ln_k<<<BT_/4, 256, 0, stream>>>(tmpo, g, bb, curB);
        }
    }

    mgemm_k<false,false,false,false,true><<<dim3(OUT_/MBN, BT_/MBM, 1), 256, 0, stream>>>(
        curB, D_, out_w, out_b, out0, OUT_, BT_, OUT_, D_,
        nullptr, nullptr, nullptr, 0);
    aux_k<<<1, 64, 0, stream>>>(impA, out2);
}